// Round 4
// baseline (297.494 us; speedup 1.0000x reference)
//
#include <hip/hip_runtime.h>
#include <math.h>

#define D 128
#define LLEN 200
#define SLEN 50
#define TSTR 136  // bf16 tile row stride (elems): 272B = 17x16B -> b128 quad=(row+oct)&7, even spread

typedef __attribute__((ext_vector_type(8))) short short8;
typedef __attribute__((ext_vector_type(4))) float f32x4;

// f32 -> bf16 round-to-nearest-even (inputs are normal embeddings; no NaN handling needed)
__device__ __forceinline__ unsigned short f2bf(float f) {
  unsigned int u = __float_as_uint(f);
  return (unsigned short)((u + 0x7FFFu + ((u >> 16) & 1u)) >> 16);
}

__device__ __forceinline__ float wave_red_sum(float v) {
#pragma unroll
  for (int m = 32; m >= 1; m >>= 1) v += __shfl_xor(v, m, 64);
  return v;
}
// 256-thread block sum; ALL threads must call.
__device__ __forceinline__ float block_sum(float v, float* red) {
  v = wave_red_sum(v);
  if ((threadIdx.x & 63) == 0) red[threadIdx.x >> 6] = v;
  __syncthreads();
  v = red[0] + red[1] + red[2] + red[3];
  __syncthreads();
  return v;
}

#define GATHER_L(dst, IT, BASE)                        \
  do {                                                 \
    int s_ = tid + (IT);                               \
    int gid_ = rows1[(BASE) + (s_ >> 5)];              \
    if (gid_ < 0) gid_ = 0;                            \
    dst = it4[(size_t)gid_ * 32 + (s_ & 31)];          \
  } while (0)

#define GATHER_S(dst, IT)                              \
  do {                                                 \
    int s_ = tid + (IT);                               \
    int gid_ = rowsS[s_ >> 5];                         \
    if (gid_ < 0) gid_ = 0;                            \
    dst = it4[(size_t)gid_ * 32 + (s_ & 31)];          \
  } while (0)

// Convert float4 -> 4x bf16, single ds_write_b64 into tile row (s>>5)+RO.
#define STOREB(src, IT, RO)                                                   \
  do {                                                                        \
    int s_ = tid + (IT);                                                      \
    ushort4 q_;                                                               \
    q_.x = f2bf(src.x); q_.y = f2bf(src.y);                                   \
    q_.z = f2bf(src.z); q_.w = f2bf(src.w);                                   \
    *reinterpret_cast<ushort4*>(&tb[((s_ >> 5) + (RO)) * TSTR +               \
                                    4 * (s_ & 31)]) = q_;                     \
  } while (0)

#define FMA4(WL, P, ACC)                \
  do {                                  \
    ACC.x = fmaf((WL), P.x, ACC.x);     \
    ACC.y = fmaf((WL), P.y, ACC.y);     \
    ACC.z = fmaf((WL), P.z, ACC.z);     \
  } while (0);                          \
  ACC.w = fmaf((WL), P.w, ACC.w)

// MFMA logits for 64 tile rows: wave w covers rows 16w..16w+15, all 16 j at once.
// A-frag: lane holds row (16w + lane&15), k = 8*(lane>>4)+t per K-step.
// C/D: j = lane&15, item = 16w + 4*(lane>>4) + reg  [m89-verified layout].
// After j-reduction (shfl over low 4 lane bits), lanes with (lane&15)==0 do
// masked exp and publish 4 weights to w_sh (one float4 write) + pacc.
template <int MODE>  // 0: L-rows (mask rowm[item]>=0 && item<nvalid); 1: stage2 ([u_long]+S)
__device__ __forceinline__ void mfma_logits(
    const unsigned short* tb, short8 Bf0, short8 Bf1, short8 Bf2, short8 Bf3,
    int w, int lane, float upart_j, float w2j, float b2v,
    const int* rowm, int nvalid, float* w_sh, float& pacc) {
  const int row = 16 * w + (lane & 15);
  const unsigned short* ap = &tb[row * TSTR + 8 * (lane >> 4)];
  short8 a0 = *reinterpret_cast<const short8*>(ap);
  short8 a1 = *reinterpret_cast<const short8*>(ap + 32);
  short8 a2 = *reinterpret_cast<const short8*>(ap + 64);
  short8 a3 = *reinterpret_cast<const short8*>(ap + 96);
  f32x4 acc = {0.f, 0.f, 0.f, 0.f};
  acc = __builtin_amdgcn_mfma_f32_16x16x32_bf16(a0, Bf0, acc, 0, 0, 0);
  acc = __builtin_amdgcn_mfma_f32_16x16x32_bf16(a1, Bf1, acc, 0, 0, 0);
  acc = __builtin_amdgcn_mfma_f32_16x16x32_bf16(a2, Bf2, acc, 0, 0, 0);
  acc = __builtin_amdgcn_mfma_f32_16x16x32_bf16(a3, Bf3, acc, 0, 0, 0);
  float v0 = fmaxf(upart_j + acc[0], 0.f) * w2j;
  float v1 = fmaxf(upart_j + acc[1], 0.f) * w2j;
  float v2 = fmaxf(upart_j + acc[2], 0.f) * w2j;
  float v3 = fmaxf(upart_j + acc[3], 0.f) * w2j;
#pragma unroll
  for (int m = 1; m <= 8; m <<= 1) {  // reduce over j = lane bits 0..3
    v0 += __shfl_xor(v0, m, 64);
    v1 += __shfl_xor(v1, m, 64);
    v2 += __shfl_xor(v2, m, 64);
    v3 += __shfl_xor(v3, m, 64);
  }
  if ((lane & 15) == 0) {
    const int it0 = 16 * w + 4 * (lane >> 4);
    float p0, p1, p2, p3;
    if (MODE == 0) {
      p0 = (it0 + 0 < nvalid && rowm[it0 + 0] >= 0) ? expf(v0 + b2v) : 0.f;
      p1 = (it0 + 1 < nvalid && rowm[it0 + 1] >= 0) ? expf(v1 + b2v) : 0.f;
      p2 = (it0 + 2 < nvalid && rowm[it0 + 2] >= 0) ? expf(v2 + b2v) : 0.f;
      p3 = (it0 + 3 < nvalid && rowm[it0 + 3] >= 0) ? expf(v3 + b2v) : 0.f;
    } else {  // item 0 = u_long (always valid); item i>=1 masked by rowm[i-1]
      p0 = (it0 == 0) ? expf(v0 + b2v)
                      : ((it0 < nvalid && rowm[it0 - 1] >= 0) ? expf(v0 + b2v) : 0.f);
      p1 = (it0 + 1 < nvalid && rowm[it0 + 0] >= 0) ? expf(v1 + b2v) : 0.f;
      p2 = (it0 + 2 < nvalid && rowm[it0 + 1] >= 0) ? expf(v2 + b2v) : 0.f;
      p3 = (it0 + 3 < nvalid && rowm[it0 + 2] >= 0) ? expf(v3 + b2v) : 0.f;
    }
    float4 pv;
    pv.x = p0; pv.y = p1; pv.z = p2; pv.w = p3;
    reinterpret_cast<float4*>(w_sh)[it0 >> 2] = pv;
    pacc += p0 + p1 + p2 + p3;
  }
}

__global__ void __launch_bounds__(256, 4) din_kernel(
    const float* __restrict__ user_table, const float* __restrict__ item_table,
    const float* __restrict__ W1, const float* __restrict__ b1,
    const float* __restrict__ W2, const float* __restrict__ b2,
    const int* __restrict__ user_inputs, const int* __restrict__ L_inputs,
    const int* __restrict__ S_inputs, const int* __restrict__ item_inputs,
    float* __restrict__ out) {
  __shared__ __align__(16) unsigned short tb[64 * TSTR];  // 17,408B bf16 tile
  __shared__ __align__(16) float scratch[512];  // prolog u_sh/part; epilog reduce
  __shared__ __align__(16) float ul_sh[128];    // u_long f32 (stage-2 accum pos 0)
  __shared__ __align__(16) float w_sh[64];      // unnormalized weights
  __shared__ int rows1[LLEN];
  __shared__ int rowsS[SLEN];
  __shared__ float upart_sh[16];
  __shared__ float red_sh[4];

  const int b = blockIdx.x;
  const int tid = threadIdx.x;
  const int lane = tid & 63;
  const int w = __builtin_amdgcn_readfirstlane(tid >> 6);
  const int col4 = tid & 31;  // float4 column (d = 4*col4..+3)
  const int grp = tid >> 5;   // row group 0..7
  const float4* it4 = reinterpret_cast<const float4*>(item_table);

  // ---- prolog: indices + user/item embeddings ----
  float* u_sh = &scratch[0];
  float* part = &scratch[128];
  if (tid < D) u_sh[tid] = user_table[(size_t)user_inputs[b] * D + tid];
  const float item_f =
      (tid < D) ? item_table[(size_t)item_inputs[b] * D + tid] : 0.f;
  if (tid < LLEN) rows1[tid] = L_inputs[(size_t)b * LLEN + tid];
  if (tid < SLEN) rowsS[tid] = S_inputs[(size_t)b * SLEN + tid];
  __syncthreads();

  // chunk-0 gathers (latency hides under B-frag build + prolog MLP)
  float4 A0, A1, A2, A3, A4, A5, A6, A7, B0, B1, B2, B3, B4, B5, B6, B7;
  GATHER_L(A0, 0, 0);    GATHER_L(A1, 256, 0);  GATHER_L(A2, 512, 0);
  GATHER_L(A3, 768, 0);  GATHER_L(A4, 1024, 0); GATHER_L(A5, 1280, 0);
  GATHER_L(A6, 1536, 0); GATHER_L(A7, 1792, 0);

  // B-fragments: W1 rows 128..255 -> bf16, per-lane layout (j = lane&15,
  // k = 32*step + 8*(lane>>4) + t). Same for all waves; W1 is L2-hot.
  short8 Bf0, Bf1, Bf2, Bf3;
  {
    const int j = lane & 15, ko = lane >> 4;
    const float* wp = &W1[(size_t)(128 + 8 * ko) * 16 + j];
#pragma unroll
    for (int t = 0; t < 8; ++t) {
      Bf0[t] = (short)f2bf(wp[t * 16]);
      Bf1[t] = (short)f2bf(wp[(32 + t) * 16]);
      Bf2[t] = (short)f2bf(wp[(64 + t) * 16]);
      Bf3[t] = (short)f2bf(wp[(96 + t) * 16]);
    }
  }

  // u_part[j] = b1[j] + u @ W1[0:128,:]  (f32, exact)
  {
    int j = tid & 15, g = tid >> 4;
    float p = 0.f;
#pragma unroll
    for (int t = 0; t < 8; ++t) {
      int d = g * 8 + t;
      p = fmaf(u_sh[d], W1[d * 16 + j], p);
    }
    part[tid] = p;
  }
  __syncthreads();
  if (tid < 16) {
    float s = b1[tid];
#pragma unroll
    for (int g = 0; g < 16; ++g) s += part[g * 16 + tid];
    upart_sh[tid] = s;
  }
  __syncthreads();

  const float b2v = b2[0];
  const float upart_j = upart_sh[lane & 15];
  const float w2j = W2[lane & 15];

  float pacc = 0.f;
  float4 uacc = make_float4(0.f, 0.f, 0.f, 0.f);
  float wl;

  // ============ chunk 0: rows 0..63 (A); prefetch B <- rows 64..127 ============
  STOREB(A0, 0, 0);    STOREB(A1, 256, 0);  STOREB(A2, 512, 0);
  STOREB(A3, 768, 0);  STOREB(A4, 1024, 0); STOREB(A5, 1280, 0);
  STOREB(A6, 1536, 0); STOREB(A7, 1792, 0);
  GATHER_L(B0, 0, 64);    GATHER_L(B1, 256, 64);  GATHER_L(B2, 512, 64);
  GATHER_L(B3, 768, 64);  GATHER_L(B4, 1024, 64); GATHER_L(B5, 1280, 64);
  GATHER_L(B6, 1536, 64); GATHER_L(B7, 1792, 64);
  __syncthreads();
  mfma_logits<0>(tb, Bf0, Bf1, Bf2, Bf3, w, lane, upart_j, w2j, b2v,
                 rows1 + 0, 64, w_sh, pacc);
  __syncthreads();
  wl = w_sh[grp];      FMA4(wl, A0, uacc);
  wl = w_sh[grp + 8];  FMA4(wl, A1, uacc);
  wl = w_sh[grp + 16]; FMA4(wl, A2, uacc);
  wl = w_sh[grp + 24]; FMA4(wl, A3, uacc);
  wl = w_sh[grp + 32]; FMA4(wl, A4, uacc);
  wl = w_sh[grp + 40]; FMA4(wl, A5, uacc);
  wl = w_sh[grp + 48]; FMA4(wl, A6, uacc);
  wl = w_sh[grp + 56]; FMA4(wl, A7, uacc);

  // ============ chunk 1: rows 64..127 (B); prefetch A <- rows 128..191 ==========
  STOREB(B0, 0, 0);    STOREB(B1, 256, 0);  STOREB(B2, 512, 0);
  STOREB(B3, 768, 0);  STOREB(B4, 1024, 0); STOREB(B5, 1280, 0);
  STOREB(B6, 1536, 0); STOREB(B7, 1792, 0);
  GATHER_L(A0, 0, 128);    GATHER_L(A1, 256, 128);  GATHER_L(A2, 512, 128);
  GATHER_L(A3, 768, 128);  GATHER_L(A4, 1024, 128); GATHER_L(A5, 1280, 128);
  GATHER_L(A6, 1536, 128); GATHER_L(A7, 1792, 128);
  __syncthreads();
  mfma_logits<0>(tb, Bf0, Bf1, Bf2, Bf3, w, lane, upart_j, w2j, b2v,
                 rows1 + 64, 64, w_sh, pacc);
  __syncthreads();
  wl = w_sh[grp];      FMA4(wl, B0, uacc);
  wl = w_sh[grp + 8];  FMA4(wl, B1, uacc);
  wl = w_sh[grp + 16]; FMA4(wl, B2, uacc);
  wl = w_sh[grp + 24]; FMA4(wl, B3, uacc);
  wl = w_sh[grp + 32]; FMA4(wl, B4, uacc);
  wl = w_sh[grp + 40]; FMA4(wl, B5, uacc);
  wl = w_sh[grp + 48]; FMA4(wl, B6, uacc);
  wl = w_sh[grp + 56]; FMA4(wl, B7, uacc);

  // ====== chunk 2: rows 128..191 (A); prefetch B0 <- tail, B1..B7 <- S rows =====
  STOREB(A0, 0, 0);    STOREB(A1, 256, 0);  STOREB(A2, 512, 0);
  STOREB(A3, 768, 0);  STOREB(A4, 1024, 0); STOREB(A5, 1280, 0);
  STOREB(A6, 1536, 0); STOREB(A7, 1792, 0);
  GATHER_L(B0, 0, 192);
  GATHER_S(B1, 0);    GATHER_S(B2, 256);  GATHER_S(B3, 512);
  GATHER_S(B4, 768);  GATHER_S(B5, 1024); GATHER_S(B6, 1280);
  if (tid < 64) GATHER_S(B7, 1536);
  __syncthreads();
  mfma_logits<0>(tb, Bf0, Bf1, Bf2, Bf3, w, lane, upart_j, w2j, b2v,
                 rows1 + 128, 64, w_sh, pacc);
  __syncthreads();
  wl = w_sh[grp];      FMA4(wl, A0, uacc);
  wl = w_sh[grp + 8];  FMA4(wl, A1, uacc);
  wl = w_sh[grp + 16]; FMA4(wl, A2, uacc);
  wl = w_sh[grp + 24]; FMA4(wl, A3, uacc);
  wl = w_sh[grp + 32]; FMA4(wl, A4, uacc);
  wl = w_sh[grp + 40]; FMA4(wl, A5, uacc);
  wl = w_sh[grp + 48]; FMA4(wl, A6, uacc);
  wl = w_sh[grp + 56]; FMA4(wl, A7, uacc);

  // ============ tail: rows 192..199 -> tile rows 0..7 (B0); wave 0 only =========
  STOREB(B0, 0, 0);
  __syncthreads();
  if (w == 0)
    mfma_logits<0>(tb, Bf0, Bf1, Bf2, Bf3, w, lane, upart_j, w2j, b2v,
                   rows1 + 192, 8, w_sh, pacc);
  __syncthreads();
  wl = w_sh[grp];
  FMA4(wl, B0, uacc);

  // ---- u_long: normalize; publish f32 row (ul_sh) + bf16 tile row 0 ----
  const float invS1 = 1.f / block_sum(pacc, red_sh);
  uacc.x += __shfl_xor(uacc.x, 32, 64);
  uacc.y += __shfl_xor(uacc.y, 32, 64);
  uacc.z += __shfl_xor(uacc.z, 32, 64);
  uacc.w += __shfl_xor(uacc.w, 32, 64);
  if (lane < 32) reinterpret_cast<float4*>(scratch)[(w << 5) + lane] = uacc;
  // S rows (B1..B7, f32 regs persist for stage-2 accum) -> tile rows 1..50
  STOREB(B1, 0, 1);    STOREB(B2, 256, 1);  STOREB(B3, 512, 1);
  STOREB(B4, 768, 1);  STOREB(B5, 1024, 1); STOREB(B6, 1280, 1);
  if (tid < 64) STOREB(B7, 1536, 1);
  __syncthreads();
  if (tid < D) {
    float s = scratch[tid] + scratch[128 + tid] + scratch[256 + tid] +
              scratch[384 + tid];
    float ul = s * invS1;
    ul_sh[tid] = ul;
    tb[tid] = f2bf(ul);  // tile row 0
  }
  __syncthreads();

  // ============ stage 2: [u_long] + 50 S rows (tile rows 0..50) ============
  float pacc2 = 0.f;
  mfma_logits<1>(tb, Bf0, Bf1, Bf2, Bf3, w, lane, upart_j, w2j, b2v,
                 rowsS, 51, w_sh, pacc2);
  const float invS2 = 1.f / block_sum(pacc2, red_sh);  // barriers publish w_sh

  float4 uacc2 = make_float4(0.f, 0.f, 0.f, 0.f);
  if (grp == 0) {  // seq pos 0 = u_long (f32 from ul_sh)
    float wl0 = w_sh[0];
    const float4 e = reinterpret_cast<const float4*>(ul_sh)[col4];
    FMA4(wl0, e, uacc2);
  }
  // S rows from f32 regs: B_it holds S-row 8*(it-1)+grp -> seq pos 1+8*(it-1)+grp
  wl = w_sh[1 + grp];  FMA4(wl, B1, uacc2);
  wl = w_sh[9 + grp];  FMA4(wl, B2, uacc2);
  wl = w_sh[17 + grp]; FMA4(wl, B3, uacc2);
  wl = w_sh[25 + grp]; FMA4(wl, B4, uacc2);
  wl = w_sh[33 + grp]; FMA4(wl, B5, uacc2);
  wl = w_sh[41 + grp]; FMA4(wl, B6, uacc2);
  if (grp < 2) { wl = w_sh[49 + grp]; FMA4(wl, B7, uacc2); }

  uacc2.x += __shfl_xor(uacc2.x, 32, 64);
  uacc2.y += __shfl_xor(uacc2.y, 32, 64);
  uacc2.z += __shfl_xor(uacc2.z, 32, 64);
  uacc2.w += __shfl_xor(uacc2.w, 32, 64);
  if (lane < 32) reinterpret_cast<float4*>(scratch)[(w << 5) + lane] = uacc2;
  __syncthreads();

  // ---- score = dot(user_hybrid, item_emb) ----
  float sv = 0.f;
  if (tid < D) {
    float s = scratch[tid] + scratch[128 + tid] + scratch[256 + tid] +
              scratch[384 + tid];
    sv = s * invS2 * item_f;
  }
  float tot = block_sum(sv, red_sh);
  if (tid == 0) out[b] = tot;
}

extern "C" void kernel_launch(void* const* d_in, const int* in_sizes, int n_in,
                              void* d_out, int out_size, void* d_ws, size_t ws_size,
                              hipStream_t stream) {
  const float* user_table = (const float*)d_in[0];
  const float* item_table = (const float*)d_in[1];
  const float* W1 = (const float*)d_in[2];
  const float* b1 = (const float*)d_in[3];
  const float* W2 = (const float*)d_in[4];
  const float* b2 = (const float*)d_in[5];
  const int* user_inputs = (const int*)d_in[6];
  const int* L_inputs = (const int*)d_in[7];
  const int* S_inputs = (const int*)d_in[8];
  const int* item_inputs = (const int*)d_in[9];
  float* out = (float*)d_out;

  const int B = in_sizes[6];  // 4096
  din_kernel<<<B, 256, 0, stream>>>(user_table, item_table, W1, b1, W2, b2,
                                    user_inputs, L_inputs, S_inputs, item_inputs,
                                    out);
}

// Round 5
// 268.717 us; speedup vs baseline: 1.1071x; 1.1071x over previous
//
#include <hip/hip_runtime.h>
#include <math.h>

#define D 128
#define LLEN 200
#define SLEN 50
#define ESTR 132  // f32 tile row stride: 528B, 16B-aligned; b128 quad=(33r+c)&7=(r+c)&7 -> uniform -> conflict-free

typedef __attribute__((ext_vector_type(8))) short short8;
typedef __attribute__((ext_vector_type(4))) float f32x4;

// f32 -> bf16 round-to-nearest-even
__device__ __forceinline__ unsigned short f2bf(float f) {
  unsigned int u = __float_as_uint(f);
  return (unsigned short)((u + 0x7FFFu + ((u >> 16) & 1u)) >> 16);
}

__device__ __forceinline__ float wave_red_sum(float v) {
#pragma unroll
  for (int m = 32; m >= 1; m >>= 1) v += __shfl_xor(v, m, 64);
  return v;
}
// 256-thread block sum; ALL threads must call.
__device__ __forceinline__ float block_sum(float v, float* red) {
  v = wave_red_sum(v);
  if ((threadIdx.x & 63) == 0) red[threadIdx.x >> 6] = v;
  __syncthreads();
  v = red[0] + red[1] + red[2] + red[3];
  __syncthreads();
  return v;
}

#define GATHER_L(dst, IT, BASE)                        \
  do {                                                 \
    int s_ = tid + (IT);                               \
    int gid_ = rows1[(BASE) + (s_ >> 5)];              \
    if (gid_ < 0) gid_ = 0;                            \
    dst = it4[(size_t)gid_ * 32 + (s_ & 31)];          \
  } while (0)

#define GATHER_S(dst, IT)                              \
  do {                                                 \
    int s_ = tid + (IT);                               \
    int gid_ = rowsS[s_ >> 5];                         \
    if (gid_ < 0) gid_ = 0;                            \
    dst = it4[(size_t)gid_ * 32 + (s_ & 31)];          \
  } while (0)

#define STORE_L(src, IT)                                                     \
  do {                                                                       \
    int s_ = tid + (IT);                                                     \
    reinterpret_cast<float4*>(&ebuf[(s_ >> 5) * ESTR])[s_ & 31] = src;       \
  } while (0)

#define STORE_S(src, IT)                                                     \
  do {                                                                       \
    int s_ = tid + (IT);                                                     \
    reinterpret_cast<float4*>(&ebuf[((s_ >> 5) + 1) * ESTR])[s_ & 31] = src; \
  } while (0)

#define FMA4(WL, P, ACC)                \
  do {                                  \
    ACC.x = fmaf((WL), P.x, ACC.x);     \
    ACC.y = fmaf((WL), P.y, ACC.y);     \
    ACC.z = fmaf((WL), P.z, ACC.z);     \
  } while (0);                          \
  ACC.w = fmaf((WL), P.w, ACC.w)

// pack two float4 (8 consecutive k) into one bf16 short8 A-fragment
#define PACK8(DST, FA, FB)                                 \
  do {                                                     \
    DST[0] = (short)f2bf(FA.x); DST[1] = (short)f2bf(FA.y);\
    DST[2] = (short)f2bf(FA.z); DST[3] = (short)f2bf(FA.w);\
    DST[4] = (short)f2bf(FB.x); DST[5] = (short)f2bf(FB.y);\
    DST[6] = (short)f2bf(FB.z); DST[7] = (short)f2bf(FB.w);\
  } while (0)

// MFMA logits for 64 tile rows: wave w covers rows 16w..16w+15, all 16 j at once.
// A-frag: lane holds row (16w + lane&15), k = 8*(lane>>4)+t (+32 per step),
// read from f32 LDS tile and converted to bf16 in-register.
// C/D: j = lane&15, item = 16w + 4*(lane>>4) + reg  [m89-verified layout].
// After j-reduction (shfl over lane bits 0..3), lanes with (lane&15)==0 do
// masked exp and publish 4 weights (one float4) to w_sh + pacc.
template <int MODE>  // 0: L-rows; 1: stage2 ([u_long] + S rows)
__device__ __forceinline__ void mfma_logits(
    const float* eb, short8 Bf0, short8 Bf1, short8 Bf2, short8 Bf3,
    int w, int lane, float upart_j, float w2j, float b2v,
    const int* rowm, int nvalid, float* w_sh, float& pacc) {
  const int row = 16 * w + (lane & 15);
  const float4* ap4 =
      reinterpret_cast<const float4*>(&eb[row * ESTR + 8 * (lane >> 4)]);
  float4 f0 = ap4[0], f1 = ap4[1];    // k + 0..7
  float4 f2 = ap4[8], f3 = ap4[9];    // k + 32..39
  float4 f4 = ap4[16], f5 = ap4[17];  // k + 64..71
  float4 f6 = ap4[24], f7 = ap4[25];  // k + 96..103
  short8 a0, a1, a2, a3;
  PACK8(a0, f0, f1); PACK8(a1, f2, f3); PACK8(a2, f4, f5); PACK8(a3, f6, f7);
  f32x4 acc = {0.f, 0.f, 0.f, 0.f};
  acc = __builtin_amdgcn_mfma_f32_16x16x32_bf16(a0, Bf0, acc, 0, 0, 0);
  acc = __builtin_amdgcn_mfma_f32_16x16x32_bf16(a1, Bf1, acc, 0, 0, 0);
  acc = __builtin_amdgcn_mfma_f32_16x16x32_bf16(a2, Bf2, acc, 0, 0, 0);
  acc = __builtin_amdgcn_mfma_f32_16x16x32_bf16(a3, Bf3, acc, 0, 0, 0);
  float v0 = fmaxf(upart_j + acc[0], 0.f) * w2j;
  float v1 = fmaxf(upart_j + acc[1], 0.f) * w2j;
  float v2 = fmaxf(upart_j + acc[2], 0.f) * w2j;
  float v3 = fmaxf(upart_j + acc[3], 0.f) * w2j;
#pragma unroll
  for (int m = 1; m <= 8; m <<= 1) {  // reduce over j = lane bits 0..3
    v0 += __shfl_xor(v0, m, 64);
    v1 += __shfl_xor(v1, m, 64);
    v2 += __shfl_xor(v2, m, 64);
    v3 += __shfl_xor(v3, m, 64);
  }
  if ((lane & 15) == 0) {
    const int it0 = 16 * w + 4 * (lane >> 4);
    float p0, p1, p2, p3;
    if (MODE == 0) {
      p0 = (it0 + 0 < nvalid && rowm[it0 + 0] >= 0) ? expf(v0 + b2v) : 0.f;
      p1 = (it0 + 1 < nvalid && rowm[it0 + 1] >= 0) ? expf(v1 + b2v) : 0.f;
      p2 = (it0 + 2 < nvalid && rowm[it0 + 2] >= 0) ? expf(v2 + b2v) : 0.f;
      p3 = (it0 + 3 < nvalid && rowm[it0 + 3] >= 0) ? expf(v3 + b2v) : 0.f;
    } else {  // item 0 = u_long (always valid); item i>=1 masked by rowm[i-1]
      p0 = (it0 == 0) ? expf(v0 + b2v)
                      : ((it0 < nvalid && rowm[it0 - 1] >= 0) ? expf(v0 + b2v) : 0.f);
      p1 = (it0 + 1 < nvalid && rowm[it0 + 0] >= 0) ? expf(v1 + b2v) : 0.f;
      p2 = (it0 + 2 < nvalid && rowm[it0 + 1] >= 0) ? expf(v2 + b2v) : 0.f;
      p3 = (it0 + 3 < nvalid && rowm[it0 + 2] >= 0) ? expf(v3 + b2v) : 0.f;
    }
    float4 pv;
    pv.x = p0; pv.y = p1; pv.z = p2; pv.w = p3;
    reinterpret_cast<float4*>(w_sh)[it0 >> 2] = pv;
    pacc += p0 + p1 + p2 + p3;
  }
}

__global__ void __launch_bounds__(256, 4) din_kernel(
    const float* __restrict__ user_table, const float* __restrict__ item_table,
    const float* __restrict__ W1, const float* __restrict__ b1,
    const float* __restrict__ W2, const float* __restrict__ b2,
    const int* __restrict__ user_inputs, const int* __restrict__ L_inputs,
    const int* __restrict__ S_inputs, const int* __restrict__ item_inputs,
    float* __restrict__ out) {
  __shared__ __align__(16) float ebuf[64 * ESTR];  // 33,792B f32 tile + aliased scratch
  __shared__ __align__(16) float w_sh[64];
  __shared__ int rows1[LLEN];
  __shared__ int rowsS[SLEN];
  __shared__ float upart_sh[16];
  __shared__ float red_sh[4];

  const int b = blockIdx.x;
  const int tid = threadIdx.x;
  const int lane = tid & 63;
  const int w = __builtin_amdgcn_readfirstlane(tid >> 6);
  const int col4 = tid & 31;  // float4 column (d = 4*col4..+3)
  const int grp = tid >> 5;   // row group 0..7
  const float4* it4 = reinterpret_cast<const float4*>(item_table);

  // ---- prolog: indices + user/item embeddings (u_sh/part alias into ebuf) ----
  float* u_sh = &ebuf[0];
  float* part = &ebuf[128];
  if (tid < D) u_sh[tid] = user_table[(size_t)user_inputs[b] * D + tid];
  const float item_f =
      (tid < D) ? item_table[(size_t)item_inputs[b] * D + tid] : 0.f;
  if (tid < LLEN) rows1[tid] = L_inputs[(size_t)b * LLEN + tid];
  if (tid < SLEN) rowsS[tid] = S_inputs[(size_t)b * SLEN + tid];
  __syncthreads();

  // chunk-0 gathers: latency hides under B-frag build + prolog MLP
  float4 P0, P1, P2, P3, P4, P5, P6, P7;
  GATHER_L(P0, 0, 0);    GATHER_L(P1, 256, 0);  GATHER_L(P2, 512, 0);
  GATHER_L(P3, 768, 0);  GATHER_L(P4, 1024, 0); GATHER_L(P5, 1280, 0);
  GATHER_L(P6, 1536, 0); GATHER_L(P7, 1792, 0);

  // B-fragments: W1 rows 128..255 -> bf16, per-lane (j = lane&15, k-block = lane>>4)
  short8 Bf0, Bf1, Bf2, Bf3;
  {
    const int j = lane & 15, ko = lane >> 4;
    const float* wp = &W1[(size_t)(128 + 8 * ko) * 16 + j];
#pragma unroll
    for (int t = 0; t < 8; ++t) {
      Bf0[t] = (short)f2bf(wp[t * 16]);
      Bf1[t] = (short)f2bf(wp[(32 + t) * 16]);
      Bf2[t] = (short)f2bf(wp[(64 + t) * 16]);
      Bf3[t] = (short)f2bf(wp[(96 + t) * 16]);
    }
  }

  // u_part[j] = b1[j] + u @ W1[0:128,:]  (f32, exact)
  {
    int j = tid & 15, g = tid >> 4;
    float p = 0.f;
#pragma unroll
    for (int t = 0; t < 8; ++t) {
      int d = g * 8 + t;
      p = fmaf(u_sh[d], W1[d * 16 + j], p);
    }
    part[tid] = p;
  }
  __syncthreads();
  if (tid < 16) {
    float s = b1[tid];
#pragma unroll
    for (int g = 0; g < 16; ++g) s += part[g * 16 + tid];
    upart_sh[tid] = s;
  }
  __syncthreads();

  const float b2v = b2[0];
  const float upart_j = upart_sh[lane & 15];
  const float w2j = W2[lane & 15];

  float pacc = 0.f;
  float4 uacc = make_float4(0.f, 0.f, 0.f, 0.f);
  float wl;

  // ============ stage 1, chunks 0..2 (64 rows each), single-buffered ============
#pragma unroll 1
  for (int c = 0; c < 3; ++c) {
    const int base = c * 64;
    // stage current chunk (regs free once writes issue)
    STORE_L(P0, 0);    STORE_L(P1, 256);  STORE_L(P2, 512);  STORE_L(P3, 768);
    STORE_L(P4, 1024); STORE_L(P5, 1280); STORE_L(P6, 1536); STORE_L(P7, 1792);
    __syncthreads();
    // prefetch next chunk (c<2) or tail+S (c==2): overlaps MFMA phase
    if (c < 2) {
      GATHER_L(P0, 0, base + 64);    GATHER_L(P1, 256, base + 64);
      GATHER_L(P2, 512, base + 64);  GATHER_L(P3, 768, base + 64);
      GATHER_L(P4, 1024, base + 64); GATHER_L(P5, 1280, base + 64);
      GATHER_L(P6, 1536, base + 64); GATHER_L(P7, 1792, base + 64);
    } else {
      GATHER_L(P0, 0, 192);  // tail: 8 rows = 256 slots
      GATHER_S(P1, 0);    GATHER_S(P2, 256);  GATHER_S(P3, 512);
      GATHER_S(P4, 768);  GATHER_S(P5, 1024); GATHER_S(P6, 1280);
      if (tid < 64) GATHER_S(P7, 1536);
    }
    mfma_logits<0>(ebuf, Bf0, Bf1, Bf2, Bf3, w, lane, upart_j, w2j, b2v,
                   rows1 + base, 64, w_sh, pacc);
    __syncthreads();  // publish w_sh
    // weighted accumulate from f32 LDS (conflict-free b128)
#pragma unroll
    for (int i = 0; i < 8; ++i) {
      int l = grp + 8 * i;
      wl = w_sh[l];
      const float4 e = reinterpret_cast<const float4*>(&ebuf[l * ESTR])[col4];
      FMA4(wl, e, uacc);
    }
    __syncthreads();  // tile reused next chunk
  }

  // ============ stage 1 tail: rows 192..199 -> tile rows 0..7 ============
  STORE_L(P0, 0);
  __syncthreads();
  if (w == 0)
    mfma_logits<0>(ebuf, Bf0, Bf1, Bf2, Bf3, w, lane, upart_j, w2j, b2v,
                   rows1 + 192, 8, w_sh, pacc);
  __syncthreads();
  wl = w_sh[grp];  // each thread reads its single tail row
  {
    const float4 e = reinterpret_cast<const float4*>(&ebuf[grp * ESTR])[col4];
    FMA4(wl, e, uacc);
  }

  // ---- u_long: block_sum + in-wave combine; scratch = dead tile rows 52..55 ----
  const float invS1 = 1.f / block_sum(pacc, red_sh);  // 1st barrier orders tail reads
  uacc.x += __shfl_xor(uacc.x, 32, 64);
  uacc.y += __shfl_xor(uacc.y, 32, 64);
  uacc.z += __shfl_xor(uacc.z, 32, 64);
  uacc.w += __shfl_xor(uacc.w, 32, 64);
  float* scr = &ebuf[52 * ESTR];  // 512 floats in rows 52..55
  if (lane < 32) reinterpret_cast<float4*>(scr)[(w << 5) + lane] = uacc;
  // S rows -> tile rows 1..50 (f32; disjoint from row 0 and scr)
  STORE_S(P1, 0);    STORE_S(P2, 256);  STORE_S(P3, 512);
  STORE_S(P4, 768);  STORE_S(P5, 1024); STORE_S(P6, 1280);
  if (tid < 64) STORE_S(P7, 1536);
  __syncthreads();
  if (tid < D) {
    float s = scr[tid] + scr[128 + tid] + scr[256 + tid] + scr[384 + tid];
    ebuf[tid] = s * invS1;  // tile row 0 = u_long (f32)
  }
  __syncthreads();

  // ============ stage 2: [u_long] + 50 S rows (tile rows 0..50) ============
  float pacc2 = 0.f;
  mfma_logits<1>(ebuf, Bf0, Bf1, Bf2, Bf3, w, lane, upart_j, w2j, b2v,
                 rowsS, 51, w_sh, pacc2);
  const float invS2 = 1.f / block_sum(pacc2, red_sh);  // barriers publish w_sh

  float4 uacc2 = make_float4(0.f, 0.f, 0.f, 0.f);
#pragma unroll
  for (int i = 0; i < 6; ++i) {
    int l = grp + 8 * i;  // rows 0..47
    wl = w_sh[l];
    const float4 e = reinterpret_cast<const float4*>(&ebuf[l * ESTR])[col4];
    FMA4(wl, e, uacc2);
  }
  if (grp < 3) {  // rows 48..50
    int l = 48 + grp;
    wl = w_sh[l];
    const float4 e = reinterpret_cast<const float4*>(&ebuf[l * ESTR])[col4];
    FMA4(wl, e, uacc2);
  }

  uacc2.x += __shfl_xor(uacc2.x, 32, 64);
  uacc2.y += __shfl_xor(uacc2.y, 32, 64);
  uacc2.z += __shfl_xor(uacc2.z, 32, 64);
  uacc2.w += __shfl_xor(uacc2.w, 32, 64);
  if (lane < 32) reinterpret_cast<float4*>(scr)[(w << 5) + lane] = uacc2;
  __syncthreads();

  // ---- score = dot(user_hybrid, item_emb) ----
  float sv = 0.f;
  if (tid < D) {
    float s = scr[tid] + scr[128 + tid] + scr[256 + tid] + scr[384 + tid];
    sv = s * invS2 * item_f;
  }
  float tot = block_sum(sv, red_sh);
  if (tid == 0) out[b] = tot;
}

extern "C" void kernel_launch(void* const* d_in, const int* in_sizes, int n_in,
                              void* d_out, int out_size, void* d_ws, size_t ws_size,
                              hipStream_t stream) {
  const float* user_table = (const float*)d_in[0];
  const float* item_table = (const float*)d_in[1];
  const float* W1 = (const float*)d_in[2];
  const float* b1 = (const float*)d_in[3];
  const float* W2 = (const float*)d_in[4];
  const float* b2 = (const float*)d_in[5];
  const int* user_inputs = (const int*)d_in[6];
  const int* L_inputs = (const int*)d_in[7];
  const int* S_inputs = (const int*)d_in[8];
  const int* item_inputs = (const int*)d_in[9];
  float* out = (float*)d_out;

  const int B = in_sizes[6];  // 4096
  din_kernel<<<B, 256, 0, stream>>>(user_table, item_table, W1, b1, W2, b2,
                                    user_inputs, L_inputs, S_inputs, item_inputs,
                                    out);
}